// Round 7
// baseline (326.663 us; speedup 1.0000x reference)
//
#include <hip/hip_runtime.h>
#include <hip/hip_bf16.h>
#include <cstddef>
#include <cstdint>

#define NN 65536
#define NE 1048576
#define BGR 64
#define SGR 1024
#define HH 128
#define BCAP 5120
#define SSTRIDE 64   // uints per node row in slots4 (256 B = 2 lines)
#define ZROWS 84     // LDS buffer rows for convfused (64 tile + halo + frag overshoot)

typedef unsigned short ushort_t;
typedef __attribute__((ext_vector_type(8))) short short8v;
typedef __attribute__((ext_vector_type(4))) float f32x4;

static __device__ inline ushort_t f2bf(float f) {
    __hip_bfloat16 h = __float2bfloat16(f);
    return *reinterpret_cast<ushort_t*>(&h);
}
static __device__ inline float bflo(unsigned int u) { return __uint_as_float(u << 16); }
static __device__ inline float bfhi(unsigned int u) { return __uint_as_float(u & 0xffff0000u); }

// ---------------- Graph prep: two-level binned slot table ----------------

__global__ __launch_bounds__(256) void binA_k(const int* __restrict__ row,
                                              const int* __restrict__ col,
                                              int* __restrict__ bucketFill,
                                              unsigned* __restrict__ region) {
    __shared__ int lcnt[256], lbase[256], lcur[256];
    int t = threadIdx.x;
    lcnt[t] = 0;
    __syncthreads();
    int e0 = blockIdx.x * 4096;
    int r[16], c[16];
    #pragma unroll
    for (int i = 0; i < 16; ++i) {
        int e = e0 + i * 256 + t;
        r[i] = row[e];
        c[i] = col[e];
        atomicAdd(&lcnt[(unsigned)c[i] >> 8], 1);
    }
    __syncthreads();
    lbase[t] = atomicAdd(&bucketFill[t], lcnt[t]);
    lcur[t] = 0;
    __syncthreads();
    #pragma unroll
    for (int i = 0; i < 16; ++i) {
        int bkt = (unsigned)c[i] >> 8;
        int pos = lbase[bkt] + atomicAdd(&lcur[bkt], 1);
        if (pos < BCAP)
            region[bkt * BCAP + pos] = ((unsigned)r[i] << 8) | ((unsigned)c[i] & 255u);
    }
}

// Pass B: degree count -> cnts+dinv, rank-scatter raw src into slots4[n][64],
// append self entry at L, pad with 0xFFFFFFFF to multiple of 8 (max 64 total).
__global__ __launch_bounds__(256) void binB_k(const unsigned* __restrict__ region,
                                              const int* __restrict__ bucketFill,
                                              unsigned* __restrict__ slots4,
                                              int* __restrict__ cnts,
                                              float* __restrict__ dinv) {
    __shared__ int deg[256], cur[256];
    int t = threadIdx.x, b = blockIdx.x;
    deg[t] = 0;
    __syncthreads();
    int cnt = min(bucketFill[b], BCAP);
    const unsigned* reg = region + b * BCAP;
    for (int i = t; i < cnt; i += 256)
        atomicAdd(&deg[reg[i] & 255u], 1);
    __syncthreads();
    int dg = deg[t];
    int n = (b << 8) + t;
    cnts[n] = dg;
    dinv[n] = rsqrtf((float)(dg + 1));
    cur[t] = 0;
    __syncthreads();
    for (int i = t; i < cnt; i += 256) {
        unsigned en = reg[i];
        int d8 = en & 255u;
        int rk = atomicAdd(&cur[d8], 1);
        if (rk < 63)
            slots4[((size_t)((b << 8) + d8)) * SSTRIDE + rk] = en >> 8;  // raw src
    }
    __syncthreads();
    int L = min(dg, 63);
    size_t base = (size_t)n * SSTRIDE;
    slots4[base + L] = (unsigned)n;                 // self-loop entry
    int E8 = (L + 8) & ~7;                          // pad entry count to x8 (<=64)
    for (int j = L + 1; j < E8; ++j) slots4[base + j] = 0xFFFFFFFFu;
}

// ---------------- GCN kernels ----------------

// Layer-1 agg on RAW x (4ch fp32) + fused h1 = relu(y@W1+b1) -> bf16.
// One wave per node, one slot entry per lane. Also folds weights into slots4.
__global__ __launch_bounds__(256) void aggx_k(const float* __restrict__ x,
                                              const int* __restrict__ cnts,
                                              const float* __restrict__ dinv,
                                              unsigned* __restrict__ slots4,
                                              const float* __restrict__ W1,
                                              const float* __restrict__ b1,
                                              ushort_t* __restrict__ h1out) {
    int w = threadIdx.x >> 6, lane = threadIdx.x & 63;
    int n = blockIdx.x * 4 + w;
    int L = min(cnts[n], 63);
    int E8 = (L + 8) & ~7;
    float dn = dinv[n];
    size_t base = (size_t)n * SSTRIDE;
    unsigned src = (unsigned)n;
    float wgt = 0.f;
    if (lane < E8) {
        unsigned e = slots4[base + lane];
        if (e != 0xFFFFFFFFu) { src = e; wgt = dn * dinv[e]; }
        slots4[base + lane] = ((unsigned)f2bf(wgt) << 16) | src;   // fold for agg2
    }
    float4 xv = *(const float4*)&x[(size_t)src * 4];
    float a0 = wgt * xv.x, a1 = wgt * xv.y, a2 = wgt * xv.z, a3 = wgt * xv.w;
    #pragma unroll
    for (int d = 1; d < 64; d <<= 1) {
        a0 += __shfl_xor(a0, d);
        a1 += __shfl_xor(a1, d);
        a2 += __shfl_xor(a2, d);
        a3 += __shfl_xor(a3, d);
    }
    // h1 pair per lane: channels c2, c2+1
    int c2 = lane * 2;
    float s0 = b1[c2]     + a0 * W1[c2]     + a1 * W1[128 + c2]     + a2 * W1[256 + c2]     + a3 * W1[384 + c2];
    float s1 = b1[c2 + 1] + a0 * W1[c2 + 1] + a1 * W1[129 + c2]     + a2 * W1[257 + c2]     + a3 * W1[385 + c2];
    s0 = fmaxf(s0, 0.f);
    s1 = fmaxf(s1, 0.f);
    unsigned p = (unsigned)f2bf(s0) | ((unsigned)f2bf(s1) << 16);
    *(unsigned*)&h1out[(size_t)n * 128 + c2] = p;
}

// out[NN,128] = A[NN,128] @ W2 via MFMA. Bt = W2^T bf16 [h][k]. out bf16.
__global__ __launch_bounds__(256) void gemm_mfma_k(const ushort_t* __restrict__ A,
                                                   const ushort_t* __restrict__ Bt,
                                                   ushort_t* __restrict__ out) {
    int t = threadIdx.x, w = t >> 6, lane = t & 63;
    int l15 = lane & 15, lk = lane >> 4;
    int n0 = blockIdx.x * 128;
    int wr = w >> 1, wc = w & 1;
    f32x4 acc[4][4] = {};
    for (int kc = 0; kc < 128; kc += 32) {
        short8v a[4], bb[4];
        #pragma unroll
        for (int nf = 0; nf < 4; ++nf)
            a[nf] = *(const short8v*)&A[(size_t)(n0 + wr * 64 + nf * 16 + l15) * 128 + kc + lk * 8];
        #pragma unroll
        for (int hf = 0; hf < 4; ++hf)
            bb[hf] = *(const short8v*)&Bt[(size_t)(wc * 64 + hf * 16 + l15) * 128 + kc + lk * 8];
        #pragma unroll
        for (int nf = 0; nf < 4; ++nf)
            #pragma unroll
            for (int hf = 0; hf < 4; ++hf)
                acc[nf][hf] = __builtin_amdgcn_mfma_f32_16x16x32_bf16(a[nf], bb[hf], acc[nf][hf], 0, 0, 0);
    }
    #pragma unroll
    for (int nf = 0; nf < 4; ++nf)
        #pragma unroll
        for (int hf = 0; hf < 4; ++hf)
            #pragma unroll
            for (int r = 0; r < 4; ++r)
                out[(size_t)(n0 + wr * 64 + nf * 16 + lk * 4 + r) * 128 + wc * 64 + hf * 16 + l15] =
                    f2bf(acc[nf][hf][r]);
}

// Layer-2 agg: quarter owns a node; 8 gathers in flight per quarter.
__global__ __launch_bounds__(256) void gcn_agg_k(const ushort_t* __restrict__ hw,
                                                 const int* __restrict__ cnts,
                                                 const unsigned* __restrict__ slots4,
                                                 const float* __restrict__ bias,
                                                 float* __restrict__ outp) {
    int w = threadIdx.x >> 6, lane = threadIdx.x & 63;
    int q = lane >> 4, l = lane & 15;
    int n = blockIdx.x * 16 + w * 4 + q;
    int c8 = l * 8;
    int L = min(cnts[n], 63);
    int iters = ((L + 8) & ~7) >> 3;
    const unsigned* sl4 = slots4 + (size_t)n * SSTRIDE;
    float a0 = 0, a1 = 0, a2 = 0, a3 = 0, a4 = 0, a5 = 0, a6 = 0, a7 = 0;
#define ACC8(v, ww) do { \
        a0 = fmaf(ww, bflo((v).x), a0); a1 = fmaf(ww, bfhi((v).x), a1); \
        a2 = fmaf(ww, bflo((v).y), a2); a3 = fmaf(ww, bfhi((v).y), a3); \
        a4 = fmaf(ww, bflo((v).z), a4); a5 = fmaf(ww, bfhi((v).z), a5); \
        a6 = fmaf(ww, bflo((v).w), a6); a7 = fmaf(ww, bfhi((v).w), a7); } while (0)
    for (int i = 0; i < iters; ++i) {
        uint4 e0 = *(const uint4*)&sl4[i * 8];
        uint4 e1 = *(const uint4*)&sl4[i * 8 + 4];
        uint4 v0 = *(const uint4*)&hw[(size_t)(e0.x & 0xffffu) * 128 + c8];
        uint4 v1 = *(const uint4*)&hw[(size_t)(e0.y & 0xffffu) * 128 + c8];
        uint4 v2 = *(const uint4*)&hw[(size_t)(e0.z & 0xffffu) * 128 + c8];
        uint4 v3 = *(const uint4*)&hw[(size_t)(e0.w & 0xffffu) * 128 + c8];
        uint4 v4 = *(const uint4*)&hw[(size_t)(e1.x & 0xffffu) * 128 + c8];
        uint4 v5 = *(const uint4*)&hw[(size_t)(e1.y & 0xffffu) * 128 + c8];
        uint4 v6 = *(const uint4*)&hw[(size_t)(e1.z & 0xffffu) * 128 + c8];
        uint4 v7 = *(const uint4*)&hw[(size_t)(e1.w & 0xffffu) * 128 + c8];
        ACC8(v0, bfhi(e0.x));
        ACC8(v1, bfhi(e0.y));
        ACC8(v2, bfhi(e0.z));
        ACC8(v3, bfhi(e0.w));
        ACC8(v4, bfhi(e1.x));
        ACC8(v5, bfhi(e1.y));
        ACC8(v6, bfhi(e1.z));
        ACC8(v7, bfhi(e1.w));
    }
#undef ACC8
    float4 b1v = *(const float4*)&bias[c8];
    float4 b2v = *(const float4*)&bias[c8 + 4];
    a0 = fmaxf(a0 + b1v.x, 0.f); a1 = fmaxf(a1 + b1v.y, 0.f);
    a2 = fmaxf(a2 + b1v.z, 0.f); a3 = fmaxf(a3 + b1v.w, 0.f);
    a4 = fmaxf(a4 + b2v.x, 0.f); a5 = fmaxf(a5 + b2v.y, 0.f);
    a6 = fmaxf(a6 + b2v.z, 0.f); a7 = fmaxf(a7 + b2v.w, 0.f);
    *(float4*)&outp[(size_t)n * 128 + c8] = make_float4(a0, a1, a2, a3);
    *(float4*)&outp[(size_t)n * 128 + c8 + 4] = make_float4(a4, a5, a6, a7);
}

// ---------------- prep: weights + output zeroing ----------------

__global__ void prep_k(const float* __restrict__ r1w1, const float* __restrict__ r1w2,
                       const float* __restrict__ r2w1, const float* __restrict__ r2w2,
                       const float* __restrict__ gW2,
                       float* __restrict__ wT1, ushort_t* __restrict__ wbB,
                       ushort_t* __restrict__ wbC, ushort_t* __restrict__ wbD,
                       ushort_t* __restrict__ w2T, float* __restrict__ gout,
                       int* __restrict__ bucketFill) {
    int gid = blockIdx.x * 256 + threadIdx.x;
    if (gid < 1536) {
        int o = gid & 127, k = (gid >> 7) % 3, ci = gid / 384;
        wT1[ci * 384 + k * 128 + o] = r1w1[o * 12 + ci * 3 + k];
    } else if (gid < 1536 + 3 * 49152) {
        int idx = gid - 1536;
        int which = idx / 49152; idx -= which * 49152;
        int ci = idx & 127, o = (idx >> 7) & 127, k = idx >> 14;
        const float* w = which == 0 ? r1w2 : (which == 1 ? r2w1 : r2w2);
        ushort_t* wb = which == 0 ? wbB : (which == 1 ? wbC : wbD);
        wb[idx] = f2bf(w[o * 384 + ci * 3 + k]);
    } else if (gid < 1536 + 3 * 49152 + 16384) {
        int idx = gid - (1536 + 3 * 49152);
        int k = idx & 127, h = idx >> 7;
        w2T[idx] = f2bf(gW2[k * 128 + h]);
    } else if (gid < 1536 + 3 * 49152 + 16384 + 8192) {
        gout[gid - (1536 + 3 * 49152 + 16384)] = 0.f;
    } else if (gid < 1536 + 3 * 49152 + 16384 + 8192 + 256) {
        bucketFill[gid - (1536 + 3 * 49152 + 16384 + 8192)] = 0;
    }
}

// ---------------- Fused conv residual path ----------------
// One block = one (batch, 64-sample tile). z1/f1/z2 in LDS with halo recompute.
// MODE: 0 = bn+relu -> LDS; 1 = +conv1x1(x) shortcut -> LDS; 2 = +residual(bufB), mean-acc.
template <int MODE>
static __device__ __forceinline__ void conv_frag(
    const ushort_t* __restrict__ src, const ushort_t* __restrict__ wb,
    const float* __restrict__ bias, const float* __restrict__ gam,
    const float* __restrict__ bet,
    int sfrag, int wr, int l15, int lk, int sbase, int s0,
    const float* __restrict__ xb, const float* __restrict__ sw,
    const float* __restrict__ sb,
    ushort_t* __restrict__ dst, const ushort_t* __restrict__ resbuf,
    float* macc) {
    f32x4 acc[4] = {};
    int rb = sfrag * 16 + l15;
    #pragma unroll
    for (int k = 0; k < 3; ++k) {
        int row = rb + k;
        const ushort_t* srow = &src[row * 128];
        int rx = row & 7;
        const ushort_t* wk = wb + k * 16384;
        #pragma unroll
        for (int cc = 0; cc < 4; ++cc) {
            int chunk = cc * 4 + lk;
            short8v bfv = *(const short8v*)&srow[(chunk ^ rx) * 8];
            #pragma unroll
            for (int of = 0; of < 4; ++of) {
                short8v av = *(const short8v*)&wk[(size_t)(wr * 64 + of * 16 + l15) * 128 + cc * 32 + lk * 8];
                acc[of] = __builtin_amdgcn_mfma_f32_16x16x32_bf16(av, bfv, acc[of], 0, 0, 0);
            }
        }
    }
    int gs = sbase + rb;               // global s of this lane's column
    bool inb = (gs >= 0 && gs < SGR);
    #pragma unroll
    for (int of = 0; of < 4; ++of) {
        int o_ = wr * 64 + of * 16 + lk * 4;
        float4 g4 = *(const float4*)&gam[o_];
        float4 b4 = *(const float4*)&bias[o_];
        float4 e4 = *(const float4*)&bet[o_];
        float v[4];
        #pragma unroll
        for (int r = 0; r < 4; ++r) v[r] = (&g4.x)[r] * (acc[of][r] + (&b4.x)[r]) + (&e4.x)[r];
        if (MODE == 1) {
            float4 xv = inb ? *(const float4*)&xb[(size_t)gs * 4] : make_float4(0, 0, 0, 0);
            float4 sb4 = *(const float4*)&sb[o_];
            #pragma unroll
            for (int r = 0; r < 4; ++r) {
                const float* swr = &sw[(o_ + r) * 4];
                v[r] += (&sb4.x)[r] + xv.x * swr[0] + xv.y * swr[1] + xv.z * swr[2] + xv.w * swr[3];
            }
        }
        int chunk = wr * 8 + of * 2 + (lk >> 1);
        int half = lk & 1;
        if (MODE == 2) {
            int rr = rb + 2;   // f1 local row for this output s
            uint2 rv = *(const uint2*)&resbuf[rr * 128 + ((chunk ^ (rr & 7)) * 8) + half * 4];
            v[0] += bflo(rv.x); v[1] += bfhi(rv.x);
            v[2] += bflo(rv.y); v[3] += bfhi(rv.y);
            #pragma unroll
            for (int r = 0; r < 4; ++r)
                macc[of * 4 + r] += inb ? fmaxf(v[r], 0.f) : 0.f;
        } else {
            uint2 p = make_uint2(0, 0);
            if (inb) {
                #pragma unroll
                for (int r = 0; r < 4; ++r) v[r] = fmaxf(v[r], 0.f);
                p.x = (unsigned)f2bf(v[0]) | ((unsigned)f2bf(v[1]) << 16);
                p.y = (unsigned)f2bf(v[2]) | ((unsigned)f2bf(v[3]) << 16);
            }
            *(uint2*)&dst[rb * 128 + ((chunk ^ (rb & 7)) * 8) + half * 4] = p;
        }
    }
}

__global__ __launch_bounds__(512) void convfused_k(
    const float* __restrict__ x, const float* __restrict__ wT1,
    const float* __restrict__ b1, const float* __restrict__ g1, const float* __restrict__ be1,
    const float* __restrict__ sw, const float* __restrict__ sb,
    const ushort_t* __restrict__ wbB, const float* __restrict__ b2,
    const float* __restrict__ g2, const float* __restrict__ be2,
    const ushort_t* __restrict__ wbC, const float* __restrict__ b3,
    const float* __restrict__ g3, const float* __restrict__ be3,
    const ushort_t* __restrict__ wbD, const float* __restrict__ b4,
    const float* __restrict__ g4, const float* __restrict__ be4,
    float* __restrict__ gout) {
    __shared__ ushort_t bufA[ZROWS * 128];   // z1, then z2
    __shared__ ushort_t bufB[ZROWS * 128];   // f1
    int t = threadIdx.x;
    int b = blockIdx.x >> 4, tile = blockIdx.x & 15;
    int s0 = tile * 64;
    const float* xb = x + (size_t)b * SGR * 4;
    // zero overshoot rows 70..83 of both buffers (896 uints each)
    for (int i = t; i < 896; i += 512) {
        ((unsigned*)bufA)[70 * 64 + i] = 0u;
        ((unsigned*)bufB)[70 * 64 + i] = 0u;
    }
    // ---- convA: z1 rows 0..69 (s = s0-3+r), fp32 VALU, 4 input ch ----
    for (int idx = t; idx < 70 * 16; idx += 512) {
        int r = idx >> 4, c = idx & 15;
        int s = s0 - 3 + r;
        uint4 pk = make_uint4(0, 0, 0, 0);
        if (s >= 0 && s < SGR) {
            float acc[8] = {0, 0, 0, 0, 0, 0, 0, 0};
            #pragma unroll
            for (int k = 0; k < 3; ++k) {
                int ss = s + k - 1;
                if (ss >= 0 && ss < SGR) {
                    float4 xv = *(const float4*)&xb[(size_t)ss * 4];
                    const float* wp = &wT1[k * 128 + c * 8];
                    #pragma unroll
                    for (int ci = 0; ci < 4; ++ci) {
                        float xc = (&xv.x)[ci];
                        const float* w8 = wp + ci * 384;
                        #pragma unroll
                        for (int j = 0; j < 8; ++j) acc[j] = fmaf(xc, w8[j], acc[j]);
                    }
                }
            }
            const float* gp = &g1[c * 8];
            const float* bp = &b1[c * 8];
            const float* ep = &be1[c * 8];
            unsigned po[4];
            #pragma unroll
            for (int jj = 0; jj < 4; ++jj) {
                float v0 = fmaxf(gp[jj * 2] * (acc[jj * 2] + bp[jj * 2]) + ep[jj * 2], 0.f);
                float v1 = fmaxf(gp[jj * 2 + 1] * (acc[jj * 2 + 1] + bp[jj * 2 + 1]) + ep[jj * 2 + 1], 0.f);
                po[jj] = (unsigned)f2bf(v0) | ((unsigned)f2bf(v1) << 16);
            }
            pk = make_uint4(po[0], po[1], po[2], po[3]);
        }
        *(uint4*)&bufA[r * 128 + ((c ^ (r & 7)) * 8)] = pk;
    }
    __syncthreads();
    int w = t >> 6, lane = t & 63;
    int wr = w >> 2, wc = w & 3;
    int l15 = lane & 15, lk = lane >> 4;
    // ---- convB: f1 (5 frags), src bufA, dst bufB, +shortcut ----
    conv_frag<1>(bufA, wbB, b2, g2, be2, wc, wr, l15, lk, s0 - 2, s0, xb, sw, sb, bufB, nullptr, nullptr);
    if (wc == 0)
        conv_frag<1>(bufA, wbB, b2, g2, be2, 4, wr, l15, lk, s0 - 2, s0, xb, sw, sb, bufB, nullptr, nullptr);
    __syncthreads();
    // ---- convC: z2 (5 frags), src bufB, dst bufA ----
    conv_frag<0>(bufB, wbC, b3, g3, be3, wc, wr, l15, lk, s0 - 1, s0, nullptr, nullptr, nullptr, bufA, nullptr, nullptr);
    if (wc == 0)
        conv_frag<0>(bufB, wbC, b3, g3, be3, 4, wr, l15, lk, s0 - 1, s0, nullptr, nullptr, nullptr, bufA, nullptr, nullptr);
    __syncthreads();
    // ---- convD: f2 (4 frags), src bufA, residual bufB, mean-pool ----
    float macc[16] = {0, 0, 0, 0, 0, 0, 0, 0, 0, 0, 0, 0, 0, 0, 0, 0};
    conv_frag<2>(bufA, wbD, b4, g4, be4, wc, wr, l15, lk, s0, s0, nullptr, nullptr, nullptr, nullptr, bufB, macc);
    #pragma unroll
    for (int of = 0; of < 4; ++of) {
        #pragma unroll
        for (int r = 0; r < 4; ++r) {
            float t2 = macc[of * 4 + r];
            t2 += __shfl_xor(t2, 1);
            t2 += __shfl_xor(t2, 2);
            t2 += __shfl_xor(t2, 4);
            t2 += __shfl_xor(t2, 8);
            if (l15 == 0)
                atomicAdd(&gout[b * 128 + wr * 64 + of * 16 + lk * 4 + r], t2 * (1.0f / 1024.0f));
        }
    }
}

// ---------------- launch ----------------

extern "C" void kernel_launch(void* const* d_in, const int* in_sizes, int n_in,
                              void* d_out, int out_size, void* d_ws, size_t ws_size,
                              hipStream_t stream) {
    const float* x    = (const float*)d_in[0];
    const int*   ei   = (const int*)d_in[1];
    const float* gW1  = (const float*)d_in[3];
    const float* gb1  = (const float*)d_in[4];
    const float* gW2  = (const float*)d_in[5];
    const float* gb2  = (const float*)d_in[6];
    const float* r1w1 = (const float*)d_in[7];
    const float* r1b1 = (const float*)d_in[8];
    const float* r1g1 = (const float*)d_in[9];
    const float* r1be1= (const float*)d_in[10];
    const float* r1w2 = (const float*)d_in[11];
    const float* r1b2 = (const float*)d_in[12];
    const float* r1g2 = (const float*)d_in[13];
    const float* r1be2= (const float*)d_in[14];
    const float* r1sw = (const float*)d_in[15];
    const float* r1sb = (const float*)d_in[16];
    const float* r2w1 = (const float*)d_in[17];
    const float* r2b1 = (const float*)d_in[18];
    const float* r2g1 = (const float*)d_in[19];
    const float* r2be1= (const float*)d_in[20];
    const float* r2w2 = (const float*)d_in[21];
    const float* r2b2 = (const float*)d_in[22];
    const float* r2g2 = (const float*)d_in[23];
    const float* r2be2= (const float*)d_in[24];

    float* hout = (float*)d_out;
    float* gout = (float*)d_out + (size_t)NN * HH;

    // workspace layout (~55 MB)
    ushort_t* bufT   = (ushort_t*)d_ws;                      // NN*128 bf16 (hw2)
    ushort_t* h1buf  = bufT + (size_t)NN * 128;              // NN*128 bf16
    unsigned* slots4 = (unsigned*)(h1buf + (size_t)NN * 128);// NN*64 uints
    unsigned* region = slots4 + (size_t)NN * SSTRIDE;        // 256*BCAP
    ushort_t* wbB    = (ushort_t*)(region + 256 * BCAP);     // 3*128*128
    ushort_t* wbC    = wbB + 49152;
    ushort_t* wbD    = wbC + 49152;
    ushort_t* w2T    = wbD + 49152;                          // 128*128
    float* wT1       = (float*)(w2T + 16384);                // 4*3*128 fp32
    float* dinv      = wT1 + 1536;                           // NN
    int* cnts        = (int*)(dinv + NN);                    // NN
    int* bucketFill  = cnts + NN;                            // 256

    const int* row = ei;
    const int* col = ei + NE;

    // prep: weights + gout/bucketFill zeroing
    prep_k<<<679, 256, 0, stream>>>(r1w1, r1w2, r2w1, r2w2, gW2,
                                    wT1, wbB, wbC, wbD, w2T, gout, bucketFill);

    // graph prep
    binA_k<<<256, 256, 0, stream>>>(row, col, bucketFill, region);
    binB_k<<<256, 256, 0, stream>>>(region, bucketFill, slots4, cnts, dinv);

    // GCN layer 1 (reassociated, fused h1) + layer 2
    aggx_k<<<NN / 4, 256, 0, stream>>>(x, cnts, dinv, slots4, gW1, gb1, h1buf);
    gemm_mfma_k<<<NN / 128, 256, 0, stream>>>(h1buf, w2T, bufT);
    gcn_agg_k<<<NN / 16, 256, 0, stream>>>(bufT, cnts, slots4, gb2, hout);

    // fused conv residual path (x -> gout)
    convfused_k<<<BGR * 16, 512, 0, stream>>>(
        x, wT1, r1b1, r1g1, r1be1, r1sw, r1sb,
        wbB, r1b2, r1g2, r1be2,
        wbC, r2b1, r2g1, r2be1,
        wbD, r2b2, r2g2, r2be2, gout);
}

// Round 8
// 226.892 us; speedup vs baseline: 1.4397x; 1.4397x over previous
//
#include <hip/hip_runtime.h>
#include <hip/hip_bf16.h>
#include <cstddef>
#include <cstdint>

#define NN 65536
#define NE 1048576
#define BGR 64
#define SGR 1024
#define HH 128
#define BCAP 5120
#define SSTRIDE 64   // uints per node row in slots4 (256 B = 2 lines)

typedef unsigned short ushort_t;
typedef __attribute__((ext_vector_type(8))) short short8v;
typedef __attribute__((ext_vector_type(4))) float f32x4;

static __device__ inline ushort_t f2bf(float f) {
    __hip_bfloat16 h = __float2bfloat16(f);
    return *reinterpret_cast<ushort_t*>(&h);
}
static __device__ inline float bflo(unsigned int u) { return __uint_as_float(u << 16); }
static __device__ inline float bfhi(unsigned int u) { return __uint_as_float(u & 0xffff0000u); }

// ---------------- Graph prep: two-level binned slot table ----------------

__global__ __launch_bounds__(256) void binA_k(const int* __restrict__ row,
                                              const int* __restrict__ col,
                                              int* __restrict__ bucketFill,
                                              unsigned* __restrict__ region) {
    __shared__ int lcnt[256], lbase[256], lcur[256];
    int t = threadIdx.x;
    lcnt[t] = 0;
    __syncthreads();
    int e0 = blockIdx.x * 4096;
    int r[16], c[16];
    #pragma unroll
    for (int i = 0; i < 16; ++i) {
        int e = e0 + i * 256 + t;
        r[i] = row[e];
        c[i] = col[e];
        atomicAdd(&lcnt[(unsigned)c[i] >> 8], 1);
    }
    __syncthreads();
    lbase[t] = atomicAdd(&bucketFill[t], lcnt[t]);
    lcur[t] = 0;
    __syncthreads();
    #pragma unroll
    for (int i = 0; i < 16; ++i) {
        int bkt = (unsigned)c[i] >> 8;
        int pos = lbase[bkt] + atomicAdd(&lcur[bkt], 1);
        if (pos < BCAP)
            region[bkt * BCAP + pos] = ((unsigned)r[i] << 8) | ((unsigned)c[i] & 255u);
    }
}

// Pass B: degree count -> cnts+dinv, rank-scatter raw src into slots4[n][64],
// append self entry at L, pad with 0xFFFFFFFF to multiple of 8 (max 64 total).
__global__ __launch_bounds__(256) void binB_k(const unsigned* __restrict__ region,
                                              const int* __restrict__ bucketFill,
                                              unsigned* __restrict__ slots4,
                                              int* __restrict__ cnts,
                                              float* __restrict__ dinv) {
    __shared__ int deg[256], cur[256];
    int t = threadIdx.x, b = blockIdx.x;
    deg[t] = 0;
    __syncthreads();
    int cnt = min(bucketFill[b], BCAP);
    const unsigned* reg = region + b * BCAP;
    for (int i = t; i < cnt; i += 256)
        atomicAdd(&deg[reg[i] & 255u], 1);
    __syncthreads();
    int dg = deg[t];
    int n = (b << 8) + t;
    cnts[n] = dg;
    dinv[n] = rsqrtf((float)(dg + 1));
    cur[t] = 0;
    __syncthreads();
    for (int i = t; i < cnt; i += 256) {
        unsigned en = reg[i];
        int d8 = en & 255u;
        int rk = atomicAdd(&cur[d8], 1);
        if (rk < 63)
            slots4[((size_t)((b << 8) + d8)) * SSTRIDE + rk] = en >> 8;  // raw src
    }
    __syncthreads();
    int L = min(dg, 63);
    size_t base = (size_t)n * SSTRIDE;
    slots4[base + L] = (unsigned)n;                 // self-loop entry
    int E8 = (L + 8) & ~7;                          // pad entry count to x8 (<=64)
    for (int j = L + 1; j < E8; ++j) slots4[base + j] = 0xFFFFFFFFu;
}

// ---------------- GCN kernels ----------------

// Layer-1 agg on RAW x (4ch fp32) + fused h1 = relu(y@W1+b1) -> bf16.
// One wave per node, one slot entry per lane. Also folds weights into slots4.
__global__ __launch_bounds__(256) void aggx_k(const float* __restrict__ x,
                                              const int* __restrict__ cnts,
                                              const float* __restrict__ dinv,
                                              unsigned* __restrict__ slots4,
                                              const float* __restrict__ W1,
                                              const float* __restrict__ b1,
                                              ushort_t* __restrict__ h1out) {
    int w = threadIdx.x >> 6, lane = threadIdx.x & 63;
    int n = blockIdx.x * 4 + w;
    int L = min(cnts[n], 63);
    int E8 = (L + 8) & ~7;
    float dn = dinv[n];
    size_t base = (size_t)n * SSTRIDE;
    unsigned src = (unsigned)n;
    float wgt = 0.f;
    if (lane < E8) {
        unsigned e = slots4[base + lane];
        if (e != 0xFFFFFFFFu) { src = e; wgt = dn * dinv[e]; }
        slots4[base + lane] = ((unsigned)f2bf(wgt) << 16) | src;   // fold for agg2
    }
    float4 xv = *(const float4*)&x[(size_t)src * 4];
    float a0 = wgt * xv.x, a1 = wgt * xv.y, a2 = wgt * xv.z, a3 = wgt * xv.w;
    #pragma unroll
    for (int d = 1; d < 64; d <<= 1) {
        a0 += __shfl_xor(a0, d);
        a1 += __shfl_xor(a1, d);
        a2 += __shfl_xor(a2, d);
        a3 += __shfl_xor(a3, d);
    }
    // h1 pair per lane: channels c2, c2+1
    int c2 = lane * 2;
    float s0 = b1[c2]     + a0 * W1[c2]     + a1 * W1[128 + c2] + a2 * W1[256 + c2] + a3 * W1[384 + c2];
    float s1 = b1[c2 + 1] + a0 * W1[c2 + 1] + a1 * W1[129 + c2] + a2 * W1[257 + c2] + a3 * W1[385 + c2];
    s0 = fmaxf(s0, 0.f);
    s1 = fmaxf(s1, 0.f);
    unsigned p = (unsigned)f2bf(s0) | ((unsigned)f2bf(s1) << 16);
    *(unsigned*)&h1out[(size_t)n * 128 + c2] = p;
}

// out[NN,128] = A[NN,128] @ W2 via MFMA. Bt = W2^T bf16 [h][k]. out bf16.
__global__ __launch_bounds__(256) void gemm_mfma_k(const ushort_t* __restrict__ A,
                                                   const ushort_t* __restrict__ Bt,
                                                   ushort_t* __restrict__ out) {
    int t = threadIdx.x, w = t >> 6, lane = t & 63;
    int l15 = lane & 15, lk = lane >> 4;
    int n0 = blockIdx.x * 128;
    int wr = w >> 1, wc = w & 1;
    f32x4 acc[4][4] = {};
    for (int kc = 0; kc < 128; kc += 32) {
        short8v a[4], bb[4];
        #pragma unroll
        for (int nf = 0; nf < 4; ++nf)
            a[nf] = *(const short8v*)&A[(size_t)(n0 + wr * 64 + nf * 16 + l15) * 128 + kc + lk * 8];
        #pragma unroll
        for (int hf = 0; hf < 4; ++hf)
            bb[hf] = *(const short8v*)&Bt[(size_t)(wc * 64 + hf * 16 + l15) * 128 + kc + lk * 8];
        #pragma unroll
        for (int nf = 0; nf < 4; ++nf)
            #pragma unroll
            for (int hf = 0; hf < 4; ++hf)
                acc[nf][hf] = __builtin_amdgcn_mfma_f32_16x16x32_bf16(a[nf], bb[hf], acc[nf][hf], 0, 0, 0);
    }
    #pragma unroll
    for (int nf = 0; nf < 4; ++nf)
        #pragma unroll
        for (int hf = 0; hf < 4; ++hf)
            #pragma unroll
            for (int r = 0; r < 4; ++r)
                out[(size_t)(n0 + wr * 64 + nf * 16 + lk * 4 + r) * 128 + wc * 64 + hf * 16 + l15] =
                    f2bf(acc[nf][hf][r]);
}

// Layer-2 agg: quarter owns a node; 8 gathers in flight per quarter.
__global__ __launch_bounds__(256) void gcn_agg_k(const ushort_t* __restrict__ hw,
                                                 const int* __restrict__ cnts,
                                                 const unsigned* __restrict__ slots4,
                                                 const float* __restrict__ bias,
                                                 float* __restrict__ outp) {
    int w = threadIdx.x >> 6, lane = threadIdx.x & 63;
    int q = lane >> 4, l = lane & 15;
    int n = blockIdx.x * 16 + w * 4 + q;
    int c8 = l * 8;
    int L = min(cnts[n], 63);
    int iters = ((L + 8) & ~7) >> 3;
    const unsigned* sl4 = slots4 + (size_t)n * SSTRIDE;
    float a0 = 0, a1 = 0, a2 = 0, a3 = 0, a4 = 0, a5 = 0, a6 = 0, a7 = 0;
#define ACC8(v, ww) do { \
        a0 = fmaf(ww, bflo((v).x), a0); a1 = fmaf(ww, bfhi((v).x), a1); \
        a2 = fmaf(ww, bflo((v).y), a2); a3 = fmaf(ww, bfhi((v).y), a3); \
        a4 = fmaf(ww, bflo((v).z), a4); a5 = fmaf(ww, bfhi((v).z), a5); \
        a6 = fmaf(ww, bflo((v).w), a6); a7 = fmaf(ww, bfhi((v).w), a7); } while (0)
    for (int i = 0; i < iters; ++i) {
        uint4 e0 = *(const uint4*)&sl4[i * 8];
        uint4 e1 = *(const uint4*)&sl4[i * 8 + 4];
        uint4 v0 = *(const uint4*)&hw[(size_t)(e0.x & 0xffffu) * 128 + c8];
        uint4 v1 = *(const uint4*)&hw[(size_t)(e0.y & 0xffffu) * 128 + c8];
        uint4 v2 = *(const uint4*)&hw[(size_t)(e0.z & 0xffffu) * 128 + c8];
        uint4 v3 = *(const uint4*)&hw[(size_t)(e0.w & 0xffffu) * 128 + c8];
        uint4 v4 = *(const uint4*)&hw[(size_t)(e1.x & 0xffffu) * 128 + c8];
        uint4 v5 = *(const uint4*)&hw[(size_t)(e1.y & 0xffffu) * 128 + c8];
        uint4 v6 = *(const uint4*)&hw[(size_t)(e1.z & 0xffffu) * 128 + c8];
        uint4 v7 = *(const uint4*)&hw[(size_t)(e1.w & 0xffffu) * 128 + c8];
        ACC8(v0, bfhi(e0.x));
        ACC8(v1, bfhi(e0.y));
        ACC8(v2, bfhi(e0.z));
        ACC8(v3, bfhi(e0.w));
        ACC8(v4, bfhi(e1.x));
        ACC8(v5, bfhi(e1.y));
        ACC8(v6, bfhi(e1.z));
        ACC8(v7, bfhi(e1.w));
    }
#undef ACC8
    float4 b1v = *(const float4*)&bias[c8];
    float4 b2v = *(const float4*)&bias[c8 + 4];
    a0 = fmaxf(a0 + b1v.x, 0.f); a1 = fmaxf(a1 + b1v.y, 0.f);
    a2 = fmaxf(a2 + b1v.z, 0.f); a3 = fmaxf(a3 + b1v.w, 0.f);
    a4 = fmaxf(a4 + b2v.x, 0.f); a5 = fmaxf(a5 + b2v.y, 0.f);
    a6 = fmaxf(a6 + b2v.z, 0.f); a7 = fmaxf(a7 + b2v.w, 0.f);
    *(float4*)&outp[(size_t)n * 128 + c8] = make_float4(a0, a1, a2, a3);
    *(float4*)&outp[(size_t)n * 128 + c8 + 4] = make_float4(a4, a5, a6, a7);
}

// ---------------- prep: weights + pad/output zeroing ----------------

__global__ void prep_k(const float* __restrict__ r1w1, const float* __restrict__ r1w2,
                       const float* __restrict__ r2w1, const float* __restrict__ r2w2,
                       const float* __restrict__ gW2,
                       float* __restrict__ wT1, ushort_t* __restrict__ wbB,
                       ushort_t* __restrict__ wbC, ushort_t* __restrict__ wbD,
                       ushort_t* __restrict__ w2T, ushort_t* __restrict__ zA,
                       ushort_t* __restrict__ f1, float* __restrict__ gout,
                       int* __restrict__ bucketFill) {
    int gid = blockIdx.x * 256 + threadIdx.x;
    if (gid < 1536) {
        int o = gid & 127, k = (gid >> 7) % 3, ci = gid / 384;
        wT1[ci * 384 + k * 128 + o] = r1w1[o * 12 + ci * 3 + k];
    } else if (gid < 1536 + 3 * 49152) {
        int idx = gid - 1536;
        int which = idx / 49152; idx -= which * 49152;
        int ci = idx & 127, o = (idx >> 7) & 127, k = idx >> 14;
        const float* w = which == 0 ? r1w2 : (which == 1 ? r2w1 : r2w2);
        ushort_t* wb = which == 0 ? wbB : (which == 1 ? wbC : wbD);
        wb[idx] = f2bf(w[o * 384 + ci * 3 + k]);
    } else if (gid < 1536 + 3 * 49152 + 16384) {
        int idx = gid - (1536 + 3 * 49152);
        int k = idx & 127, h = idx >> 7;
        w2T[idx] = f2bf(gW2[k * 128 + h]);
    } else if (gid < 1536 + 3 * 49152 + 16384 + 16384) {
        int idx = gid - (1536 + 3 * 49152 + 16384);
        int b = idx >> 8, r = (idx >> 7) & 1, c = idx & 127;
        size_t off = ((size_t)b * 1026 + (r ? 1025 : 0)) * 128 + c;
        zA[off] = 0;
        f1[off] = 0;
    } else if (gid < 1536 + 3 * 49152 + 16384 + 16384 + 8192) {
        gout[gid - (1536 + 3 * 49152 + 16384 + 16384)] = 0.f;
    } else if (gid < 1536 + 3 * 49152 + 16384 + 16384 + 8192 + 256) {
        bucketFill[gid - (1536 + 3 * 49152 + 16384 + 16384 + 8192)] = 0;
    }
}

// ---------------- Conv path (round-6 known-good 4-kernel chain) ----------------

// convA: z1 = relu(bn1(conv1(x))) and sc = conv1x1(x,sw)+sb, both bf16 [b][s][o]
__global__ __launch_bounds__(256) void convA_k(
    const float* __restrict__ x, const float* __restrict__ wT,
    const float* __restrict__ b1, const float* __restrict__ g1, const float* __restrict__ be1,
    const float* __restrict__ sw, const float* __restrict__ sb,
    ushort_t* __restrict__ z1, ushort_t* __restrict__ sc) {
    __shared__ float wl[4 * 384];
    __shared__ float zl[4][66];
    int t = threadIdx.x;
    int b = blockIdx.x >> 4, tile = blockIdx.x & 15;
    int s0 = tile * 64;
    int og = t & 31, sg = t >> 5, o0 = og * 4;
    for (int idx = t; idx < 4 * 384; idx += 256) wl[idx] = wT[idx];
    for (int idx = t; idx < 4 * 66; idx += 256) {
        int cl = idx / 66, pos = idx % 66;
        int s = s0 - 1 + pos;
        zl[cl][pos] = (s >= 0 && s < SGR) ? x[((size_t)b * SGR + s) * 4 + cl] : 0.f;
    }
    __syncthreads();
    float acc[4][8] = {};
    float scv[4][8] = {};
    for (int cl = 0; cl < 4; ++cl) {
        float sws[4];
        #pragma unroll
        for (int oi = 0; oi < 4; ++oi) sws[oi] = sw[(o0 + oi) * 4 + cl];
        #pragma unroll
        for (int k = 0; k < 3; ++k) {
            const float4 wv = *(const float4*)&wl[cl * 384 + k * 128 + o0];
            float wvv[4] = {wv.x, wv.y, wv.z, wv.w};
            #pragma unroll
            for (int j = 0; j < 8; ++j) {
                float zv = zl[cl][sg * 8 + j + k];
                #pragma unroll
                for (int oi = 0; oi < 4; ++oi) acc[oi][j] += wvv[oi] * zv;
            }
        }
        #pragma unroll
        for (int j = 0; j < 8; ++j) {
            float zc = zl[cl][sg * 8 + j + 1];
            #pragma unroll
            for (int oi = 0; oi < 4; ++oi) scv[oi][j] += sws[oi] * zc;
        }
    }
    float gg[4], bbv[4], eev[4], sbv[4];
    #pragma unroll
    for (int oi = 0; oi < 4; ++oi) {
        int o = o0 + oi;
        gg[oi] = g1[o]; bbv[oi] = b1[o]; eev[oi] = be1[o]; sbv[oi] = sb[o];
    }
    #pragma unroll
    for (int j = 0; j < 8; ++j) {
        int s = s0 + sg * 8 + j;
        uint64_t pz = 0, ps = 0;
        #pragma unroll
        for (int oi = 0; oi < 4; ++oi) {
            float v = gg[oi] * (acc[oi][j] + bbv[oi]) + eev[oi];
            v = fmaxf(v, 0.f);
            pz |= (uint64_t)f2bf(v) << (16 * oi);
            ps |= (uint64_t)f2bf(scv[oi][j] + sbv[oi]) << (16 * oi);
        }
        *(uint64_t*)&z1[((size_t)b * 1026 + 1 + s) * 128 + o0] = pz;
        *(uint64_t*)&sc[((size_t)b * SGR + s) * 128 + o0] = ps;
    }
}

// MFMA conv: out(o,s) = epilogue( sum_{k,ci} w[k][o][ci] * z[s+k-1][ci] )
// MODE 0: relu(bn) -> padded buf; MODE 1: + sc shortcut; MODE 2: + residual, mean->gout
template <int MODE>
__global__ __launch_bounds__(512) void conv_mfma_k(
    const ushort_t* __restrict__ zin, const ushort_t* __restrict__ wb,
    const float* __restrict__ bias, const float* __restrict__ gam,
    const float* __restrict__ bet, const ushort_t* __restrict__ res,
    void* __restrict__ outp) {
    __shared__ ushort_t zl[130 * 128];
    int t = threadIdx.x;
    int b = blockIdx.x >> 3, s0 = (blockIdx.x & 7) << 7;
    const ushort_t* zg = zin + ((size_t)b * 1026 + s0) * 128;
    for (int idx = t; idx < 130 * 16; idx += 512) {
        int r = idx >> 4, c = idx & 15;
        *(short8v*)&zl[r * 128 + c * 8] = *(const short8v*)&zg[(size_t)r * 128 + ((c ^ (r & 7)) * 8)];
    }
    __syncthreads();
    int w = t >> 6, lane = t & 63;
    int wr = w >> 2, wc = w & 3;
    int l15 = lane & 15, lk = lane >> 4;
    f32x4 acc[4][2] = {};
    #pragma unroll
    for (int k = 0; k < 3; ++k) {
        const ushort_t* wk = wb + k * 16384;
        #pragma unroll
        for (int cc = 0; cc < 4; ++cc) {
            int ci0 = cc * 32 + lk * 8;
            short8v a[4], bf[2];
            #pragma unroll
            for (int of = 0; of < 4; ++of)
                a[of] = *(const short8v*)&wk[(size_t)(wr * 64 + of * 16 + l15) * 128 + ci0];
            #pragma unroll
            for (int sf = 0; sf < 2; ++sf) {
                int r = wc * 32 + sf * 16 + l15 + k;
                int chunk = (cc * 4 + lk) ^ (r & 7);
                bf[sf] = *(const short8v*)&zl[r * 128 + chunk * 8];
            }
            #pragma unroll
            for (int of = 0; of < 4; ++of)
                #pragma unroll
                for (int sf = 0; sf < 2; ++sf)
                    acc[of][sf] = __builtin_amdgcn_mfma_f32_16x16x32_bf16(a[of], bf[sf], acc[of][sf], 0, 0, 0);
        }
    }
    float psum[4][4];
    if (MODE == 2)
        #pragma unroll
        for (int of = 0; of < 4; ++of)
            #pragma unroll
            for (int r = 0; r < 4; ++r) psum[of][r] = 0.f;
    #pragma unroll
    for (int of = 0; of < 4; ++of) {
        int o_ = wr * 64 + of * 16 + lk * 4;
        float g4[4], b4[4], e4[4];
        *(float4*)g4 = *(const float4*)&gam[o_];
        *(float4*)b4 = *(const float4*)&bias[o_];
        *(float4*)e4 = *(const float4*)&bet[o_];
        #pragma unroll
        for (int sf = 0; sf < 2; ++sf) {
            int s_ = s0 + wc * 32 + sf * 16 + l15;
            float v[4];
            #pragma unroll
            for (int r = 0; r < 4; ++r) v[r] = g4[r] * (acc[of][sf][r] + b4[r]) + e4[r];
            if (MODE == 1) {
                uint2 rv = *(const uint2*)&res[((size_t)b * SGR + s_) * 128 + o_];
                v[0] += bflo(rv.x); v[1] += bfhi(rv.x);
                v[2] += bflo(rv.y); v[3] += bfhi(rv.y);
            }
            if (MODE == 2) {
                uint2 rv = *(const uint2*)&res[((size_t)b * 1026 + 1 + s_) * 128 + o_];
                v[0] += bflo(rv.x); v[1] += bfhi(rv.x);
                v[2] += bflo(rv.y); v[3] += bfhi(rv.y);
            }
            #pragma unroll
            for (int r = 0; r < 4; ++r) v[r] = fmaxf(v[r], 0.f);
            if (MODE <= 1) {
                uint64_t p = (uint64_t)f2bf(v[0]) | ((uint64_t)f2bf(v[1]) << 16) |
                             ((uint64_t)f2bf(v[2]) << 32) | ((uint64_t)f2bf(v[3]) << 48);
                *(uint64_t*)&((ushort_t*)outp)[((size_t)b * 1026 + 1 + s_) * 128 + o_] = p;
            } else {
                #pragma unroll
                for (int r = 0; r < 4; ++r) psum[of][r] += v[r];
            }
        }
    }
    if (MODE == 2) {
        float* gout = (float*)outp;
        #pragma unroll
        for (int of = 0; of < 4; ++of) {
            #pragma unroll
            for (int r = 0; r < 4; ++r) {
                float t2 = psum[of][r];
                t2 += __shfl_xor(t2, 1);
                t2 += __shfl_xor(t2, 2);
                t2 += __shfl_xor(t2, 4);
                t2 += __shfl_xor(t2, 8);
                if (l15 == 0)
                    atomicAdd(&gout[b * 128 + wr * 64 + of * 16 + lk * 4 + r], t2 * (1.0f / 1024.0f));
            }
        }
    }
}

// ---------------- launch ----------------

extern "C" void kernel_launch(void* const* d_in, const int* in_sizes, int n_in,
                              void* d_out, int out_size, void* d_ws, size_t ws_size,
                              hipStream_t stream) {
    const float* x    = (const float*)d_in[0];
    const int*   ei   = (const int*)d_in[1];
    const float* gW1  = (const float*)d_in[3];
    const float* gb1  = (const float*)d_in[4];
    const float* gW2  = (const float*)d_in[5];
    const float* gb2  = (const float*)d_in[6];
    const float* r1w1 = (const float*)d_in[7];
    const float* r1b1 = (const float*)d_in[8];
    const float* r1g1 = (const float*)d_in[9];
    const float* r1be1= (const float*)d_in[10];
    const float* r1w2 = (const float*)d_in[11];
    const float* r1b2 = (const float*)d_in[12];
    const float* r1g2 = (const float*)d_in[13];
    const float* r1be2= (const float*)d_in[14];
    const float* r1sw = (const float*)d_in[15];
    const float* r1sb = (const float*)d_in[16];
    const float* r2w1 = (const float*)d_in[17];
    const float* r2b1 = (const float*)d_in[18];
    const float* r2g1 = (const float*)d_in[19];
    const float* r2be1= (const float*)d_in[20];
    const float* r2w2 = (const float*)d_in[21];
    const float* r2b2 = (const float*)d_in[22];
    const float* r2g2 = (const float*)d_in[23];
    const float* r2be2= (const float*)d_in[24];

    float* hout = (float*)d_out;
    float* gout = (float*)d_out + (size_t)NN * HH;

    // workspace layout (~90 MB); scb doubles as h1 buffer during the GCN phase
    ushort_t* bufT = (ushort_t*)d_ws;                 // NN*128 bf16 (hw2)
    ushort_t* zA   = bufT + (size_t)NN * 128;         // 64*1026*128
    ushort_t* f1   = zA + (size_t)64 * 1026 * 128;    // 64*1026*128
    ushort_t* scb  = f1 + (size_t)64 * 1026 * 128;    // 64*1024*128 (= h1 in GCN phase)
    unsigned* slots4 = (unsigned*)(scb + (size_t)64 * 1024 * 128);  // NN*64 uints
    unsigned* region = slots4 + (size_t)NN * SSTRIDE; // 256*BCAP
    ushort_t* wbB  = (ushort_t*)(region + 256 * BCAP);// 3*128*128
    ushort_t* wbC  = wbB + 49152;
    ushort_t* wbD  = wbC + 49152;
    ushort_t* w2T  = wbD + 49152;                     // 128*128
    float* wT1     = (float*)(w2T + 16384);           // 4*3*128 fp32
    float* dinv    = wT1 + 1536;                      // NN
    int* cnts      = (int*)(dinv + NN);               // NN
    int* bucketFill= cnts + NN;                       // 256

    const int* row = ei;
    const int* col = ei + NE;
    ushort_t* h1buf = scb;

    // prep: weights + pad zeroing + gout/bucketFill zeroing
    prep_k<<<743, 256, 0, stream>>>(r1w1, r1w2, r2w1, r2w2, gW2,
                                    wT1, wbB, wbC, wbD, w2T, zA, f1, gout, bucketFill);

    // graph prep
    binA_k<<<256, 256, 0, stream>>>(row, col, bucketFill, region);
    binB_k<<<256, 256, 0, stream>>>(region, bucketFill, slots4, cnts, dinv);

    // GCN layer 1 (reassociated, fused h1) + layer 2
    aggx_k<<<NN / 4, 256, 0, stream>>>(x, cnts, dinv, slots4, gW1, gb1, h1buf);
    gemm_mfma_k<<<NN / 128, 256, 0, stream>>>(h1buf, w2T, bufT);
    gcn_agg_k<<<NN / 16, 256, 0, stream>>>(bufT, cnts, slots4, gb2, hout);

    // conv residual path (round-6 structure)
    convA_k<<<BGR * 16, 256, 0, stream>>>(x, wT1, r1b1, r1g1, r1be1, r1sw, r1sb, zA, scb);
    conv_mfma_k<1><<<BGR * 8, 512, 0, stream>>>(zA, wbB, r1b2, r1g2, r1be2, scb, f1);
    conv_mfma_k<0><<<BGR * 8, 512, 0, stream>>>(f1, wbC, r2b1, r2g1, r2be1, nullptr, zA);
    conv_mfma_k<2><<<BGR * 8, 512, 0, stream>>>(zA, wbD, r2b2, r2g2, r2be2, f1, gout);
}

// Round 9
// 202.942 us; speedup vs baseline: 1.6096x; 1.1180x over previous
//
#include <hip/hip_runtime.h>
#include <hip/hip_bf16.h>
#include <cstddef>
#include <cstdint>

#define NN 65536
#define NE 1048576
#define BGR 64
#define SGR 1024
#define HH 128
#define BCAP 5120
#define SSTRIDE 64   // uints per node row in slots4 (256 B)

typedef unsigned short ushort_t;
typedef __attribute__((ext_vector_type(8))) short short8v;
typedef __attribute__((ext_vector_type(4))) float f32x4;

static __device__ inline ushort_t f2bf(float f) {
    __hip_bfloat16 h = __float2bfloat16(f);
    return *reinterpret_cast<ushort_t*>(&h);
}
static __device__ inline float bflo(unsigned int u) { return __uint_as_float(u << 16); }
static __device__ inline float bfhi(unsigned int u) { return __uint_as_float(u & 0xffff0000u); }

// ---------------- prep: weights + pad/output zeroing (launch 1) ----------------

__global__ void prep_k(const float* __restrict__ r1w1, const float* __restrict__ r1w2,
                       const float* __restrict__ r2w1, const float* __restrict__ r2w2,
                       const float* __restrict__ gW2,
                       float* __restrict__ wT1, ushort_t* __restrict__ wbB,
                       ushort_t* __restrict__ wbC, ushort_t* __restrict__ wbD,
                       ushort_t* __restrict__ w2T, ushort_t* __restrict__ zA,
                       ushort_t* __restrict__ f1, float* __restrict__ gout,
                       int* __restrict__ bucketFill) {
    int gid = blockIdx.x * 256 + threadIdx.x;
    if (gid < 1536) {
        int o = gid & 127, k = (gid >> 7) % 3, ci = gid / 384;
        wT1[ci * 384 + k * 128 + o] = r1w1[o * 12 + ci * 3 + k];
    } else if (gid < 1536 + 3 * 49152) {
        int idx = gid - 1536;
        int which = idx / 49152; idx -= which * 49152;
        int ci = idx & 127, o = (idx >> 7) & 127, k = idx >> 14;
        const float* w = which == 0 ? r1w2 : (which == 1 ? r2w1 : r2w2);
        ushort_t* wb = which == 0 ? wbB : (which == 1 ? wbC : wbD);
        wb[idx] = f2bf(w[o * 384 + ci * 3 + k]);
    } else if (gid < 1536 + 3 * 49152 + 16384) {
        int idx = gid - (1536 + 3 * 49152);
        int k = idx & 127, h = idx >> 7;
        w2T[idx] = f2bf(gW2[k * 128 + h]);
    } else if (gid < 1536 + 3 * 49152 + 16384 + 16384) {
        int idx = gid - (1536 + 3 * 49152 + 16384);
        int b = idx >> 8, r = (idx >> 7) & 1, c = idx & 127;
        size_t off = ((size_t)b * 1026 + (r ? 1025 : 0)) * 128 + c;
        zA[off] = 0;
        f1[off] = 0;
    } else if (gid < 1536 + 3 * 49152 + 16384 + 16384 + 8192) {
        gout[gid - (1536 + 3 * 49152 + 16384 + 16384)] = 0.f;
    } else if (gid < 1536 + 3 * 49152 + 16384 + 16384 + 8192 + 256) {
        bucketFill[gid - (1536 + 3 * 49152 + 16384 + 16384 + 8192)] = 0;
    }
}

// ---------------- graph-prep bodies ----------------

static __device__ __forceinline__ void binA_body(int blk,
        const int* __restrict__ row, const int* __restrict__ col,
        int* __restrict__ bucketFill, unsigned* __restrict__ region) {
    __shared__ int lcnt[256], lbase[256], lcur[256];
    int t = threadIdx.x;
    lcnt[t] = 0;
    __syncthreads();
    int e0 = blk * 4096;
    int r[16], c[16];
    #pragma unroll
    for (int i = 0; i < 16; ++i) {
        int e = e0 + i * 256 + t;
        r[i] = row[e];
        c[i] = col[e];
        atomicAdd(&lcnt[(unsigned)c[i] >> 8], 1);
    }
    __syncthreads();
    lbase[t] = atomicAdd(&bucketFill[t], lcnt[t]);
    lcur[t] = 0;
    __syncthreads();
    #pragma unroll
    for (int i = 0; i < 16; ++i) {
        int bkt = (unsigned)c[i] >> 8;
        int pos = lbase[bkt] + atomicAdd(&lcur[bkt], 1);
        if (pos < BCAP)
            region[bkt * BCAP + pos] = ((unsigned)r[i] << 8) | ((unsigned)c[i] & 255u);
    }
}

static __device__ __forceinline__ void binB_body(int blk,
        const unsigned* __restrict__ region, const int* __restrict__ bucketFill,
        unsigned* __restrict__ slots4, int* __restrict__ cnts, float* __restrict__ dinv) {
    __shared__ int deg[256], cur[256];
    int t = threadIdx.x, b = blk;
    deg[t] = 0;
    __syncthreads();
    int cnt = min(bucketFill[b], BCAP);
    const unsigned* reg = region + b * BCAP;
    for (int i = t; i < cnt; i += 256)
        atomicAdd(&deg[reg[i] & 255u], 1);
    __syncthreads();
    int dg = deg[t];
    int n = (b << 8) + t;
    cnts[n] = dg;
    dinv[n] = rsqrtf((float)(dg + 1));
    cur[t] = 0;
    __syncthreads();
    for (int i = t; i < cnt; i += 256) {
        unsigned en = reg[i];
        int d8 = en & 255u;
        int rk = atomicAdd(&cur[d8], 1);
        if (rk < 63)
            slots4[((size_t)((b << 8) + d8)) * SSTRIDE + rk] = en >> 8;  // raw src
    }
    __syncthreads();
    int L = min(dg, 63);
    size_t base = (size_t)n * SSTRIDE;
    slots4[base + L] = (unsigned)n;
    int E8 = (L + 8) & ~7;
    for (int j = L + 1; j < E8; ++j) slots4[base + j] = 0xFFFFFFFFu;
}

// ---------------- GCN bodies ----------------

// layer-1 agg on raw x + fused h1 = relu(y@W1+b1) -> bf16; folds weights into slots4
static __device__ __forceinline__ void aggx_body(int blk,
        const float* __restrict__ x, const int* __restrict__ cnts,
        const float* __restrict__ dinv, unsigned* __restrict__ slots4,
        const float* __restrict__ W1, const float* __restrict__ b1,
        ushort_t* __restrict__ h1out) {
    int w = threadIdx.x >> 6, lane = threadIdx.x & 63;
    int n = blk * 4 + w;
    int L = min(cnts[n], 63);
    int E8 = (L + 8) & ~7;
    float dn = dinv[n];
    size_t base = (size_t)n * SSTRIDE;
    unsigned src = (unsigned)n;
    float wgt = 0.f;
    if (lane < E8) {
        unsigned e = slots4[base + lane];
        if (e != 0xFFFFFFFFu) { src = e; wgt = dn * dinv[e]; }
        slots4[base + lane] = ((unsigned)f2bf(wgt) << 16) | src;
    }
    float4 xv = *(const float4*)&x[(size_t)src * 4];
    float a0 = wgt * xv.x, a1 = wgt * xv.y, a2 = wgt * xv.z, a3 = wgt * xv.w;
    #pragma unroll
    for (int d = 1; d < 64; d <<= 1) {
        a0 += __shfl_xor(a0, d);
        a1 += __shfl_xor(a1, d);
        a2 += __shfl_xor(a2, d);
        a3 += __shfl_xor(a3, d);
    }
    int c2 = lane * 2;
    float s0 = b1[c2]     + a0 * W1[c2]     + a1 * W1[128 + c2] + a2 * W1[256 + c2] + a3 * W1[384 + c2];
    float s1 = b1[c2 + 1] + a0 * W1[c2 + 1] + a1 * W1[129 + c2] + a2 * W1[257 + c2] + a3 * W1[385 + c2];
    s0 = fmaxf(s0, 0.f);
    s1 = fmaxf(s1, 0.f);
    unsigned p = (unsigned)f2bf(s0) | ((unsigned)f2bf(s1) << 16);
    *(unsigned*)&h1out[(size_t)n * 128 + c2] = p;
}

// layer-2 agg: Y = Ahat @ h1 (pure weighted sum), bf16 out. Solo launch.
__global__ __launch_bounds__(256) void agg2y_k(const ushort_t* __restrict__ h1,
                                               const int* __restrict__ cnts,
                                               const unsigned* __restrict__ slots4,
                                               ushort_t* __restrict__ Y) {
    int w = threadIdx.x >> 6, lane = threadIdx.x & 63;
    int q = lane >> 4, l = lane & 15;
    int n = blockIdx.x * 16 + w * 4 + q;
    int c8 = l * 8;
    int L = min(cnts[n], 63);
    int iters = ((L + 8) & ~7) >> 3;
    const unsigned* sl4 = slots4 + (size_t)n * SSTRIDE;
    float a0 = 0, a1 = 0, a2 = 0, a3 = 0, a4 = 0, a5 = 0, a6 = 0, a7 = 0;
#define ACC8(v, ww) do { \
        a0 = fmaf(ww, bflo((v).x), a0); a1 = fmaf(ww, bfhi((v).x), a1); \
        a2 = fmaf(ww, bflo((v).y), a2); a3 = fmaf(ww, bfhi((v).y), a3); \
        a4 = fmaf(ww, bflo((v).z), a4); a5 = fmaf(ww, bfhi((v).z), a5); \
        a6 = fmaf(ww, bflo((v).w), a6); a7 = fmaf(ww, bfhi((v).w), a7); } while (0)
    for (int i = 0; i < iters; ++i) {
        uint4 e0 = *(const uint4*)&sl4[i * 8];
        uint4 e1 = *(const uint4*)&sl4[i * 8 + 4];
        uint4 v0 = *(const uint4*)&h1[(size_t)(e0.x & 0xffffu) * 128 + c8];
        uint4 v1 = *(const uint4*)&h1[(size_t)(e0.y & 0xffffu) * 128 + c8];
        uint4 v2 = *(const uint4*)&h1[(size_t)(e0.z & 0xffffu) * 128 + c8];
        uint4 v3 = *(const uint4*)&h1[(size_t)(e0.w & 0xffffu) * 128 + c8];
        uint4 v4 = *(const uint4*)&h1[(size_t)(e1.x & 0xffffu) * 128 + c8];
        uint4 v5 = *(const uint4*)&h1[(size_t)(e1.y & 0xffffu) * 128 + c8];
        uint4 v6 = *(const uint4*)&h1[(size_t)(e1.z & 0xffffu) * 128 + c8];
        uint4 v7 = *(const uint4*)&h1[(size_t)(e1.w & 0xffffu) * 128 + c8];
        ACC8(v0, bfhi(e0.x));
        ACC8(v1, bfhi(e0.y));
        ACC8(v2, bfhi(e0.z));
        ACC8(v3, bfhi(e0.w));
        ACC8(v4, bfhi(e1.x));
        ACC8(v5, bfhi(e1.y));
        ACC8(v6, bfhi(e1.z));
        ACC8(v7, bfhi(e1.w));
    }
#undef ACC8
    uint4 p;
    p.x = (unsigned)f2bf(a0) | ((unsigned)f2bf(a1) << 16);
    p.y = (unsigned)f2bf(a2) | ((unsigned)f2bf(a3) << 16);
    p.z = (unsigned)f2bf(a4) | ((unsigned)f2bf(a5) << 16);
    p.w = (unsigned)f2bf(a6) | ((unsigned)f2bf(a7) << 16);
    *(uint4*)&Y[(size_t)n * 128 + c8] = p;
}

// final GEMM: hout = relu(Y @ W2 + b2), fp32 out
static __device__ __forceinline__ void gemm_body(int blk,
        const ushort_t* __restrict__ A, const ushort_t* __restrict__ Bt,
        const float* __restrict__ b2, float* __restrict__ out) {
    int t = threadIdx.x, w = t >> 6, lane = t & 63;
    int l15 = lane & 15, lk = lane >> 4;
    int n0 = blk * 128;
    int wr = w >> 1, wc = w & 1;
    f32x4 acc[4][4] = {};
    for (int kc = 0; kc < 128; kc += 32) {
        short8v a[4], bb[4];
        #pragma unroll
        for (int nf = 0; nf < 4; ++nf)
            a[nf] = *(const short8v*)&A[(size_t)(n0 + wr * 64 + nf * 16 + l15) * 128 + kc + lk * 8];
        #pragma unroll
        for (int hf = 0; hf < 4; ++hf)
            bb[hf] = *(const short8v*)&Bt[(size_t)(wc * 64 + hf * 16 + l15) * 128 + kc + lk * 8];
        #pragma unroll
        for (int nf = 0; nf < 4; ++nf)
            #pragma unroll
            for (int hf = 0; hf < 4; ++hf)
                acc[nf][hf] = __builtin_amdgcn_mfma_f32_16x16x32_bf16(a[nf], bb[hf], acc[nf][hf], 0, 0, 0);
    }
    #pragma unroll
    for (int nf = 0; nf < 4; ++nf)
        #pragma unroll
        for (int hf = 0; hf < 4; ++hf) {
            int col = wc * 64 + hf * 16 + l15;
            float bv = b2[col];
            #pragma unroll
            for (int r = 0; r < 4; ++r)
                out[(size_t)(n0 + wr * 64 + nf * 16 + lk * 4 + r) * 128 + col] =
                    fmaxf(acc[nf][hf][r] + bv, 0.f);
        }
}

// ---------------- conv bodies ----------------

// convA: z1 + shortcut, 256 threads
static __device__ __forceinline__ void convA_body(int blk,
        const float* __restrict__ x, const float* __restrict__ wT,
        const float* __restrict__ b1, const float* __restrict__ g1, const float* __restrict__ be1,
        const float* __restrict__ sw, const float* __restrict__ sb,
        ushort_t* __restrict__ z1, ushort_t* __restrict__ sc) {
    __shared__ float wl[4 * 384];
    __shared__ float zl[4][66];
    int t = threadIdx.x;
    int b = blk >> 4, tile = blk & 15;
    int s0 = tile * 64;
    int og = t & 31, sg = t >> 5, o0 = og * 4;
    for (int idx = t; idx < 4 * 384; idx += 256) wl[idx] = wT[idx];
    for (int idx = t; idx < 4 * 66; idx += 256) {
        int cl = idx / 66, pos = idx % 66;
        int s = s0 - 1 + pos;
        zl[cl][pos] = (s >= 0 && s < SGR) ? x[((size_t)b * SGR + s) * 4 + cl] : 0.f;
    }
    __syncthreads();
    float acc[4][8] = {};
    float scv[4][8] = {};
    for (int cl = 0; cl < 4; ++cl) {
        float sws[4];
        #pragma unroll
        for (int oi = 0; oi < 4; ++oi) sws[oi] = sw[(o0 + oi) * 4 + cl];
        #pragma unroll
        for (int k = 0; k < 3; ++k) {
            const float4 wv = *(const float4*)&wl[cl * 384 + k * 128 + o0];
            float wvv[4] = {wv.x, wv.y, wv.z, wv.w};
            #pragma unroll
            for (int j = 0; j < 8; ++j) {
                float zv = zl[cl][sg * 8 + j + k];
                #pragma unroll
                for (int oi = 0; oi < 4; ++oi) acc[oi][j] += wvv[oi] * zv;
            }
        }
        #pragma unroll
        for (int j = 0; j < 8; ++j) {
            float zc = zl[cl][sg * 8 + j + 1];
            #pragma unroll
            for (int oi = 0; oi < 4; ++oi) scv[oi][j] += sws[oi] * zc;
        }
    }
    float gg[4], bbv[4], eev[4], sbv[4];
    #pragma unroll
    for (int oi = 0; oi < 4; ++oi) {
        int o = o0 + oi;
        gg[oi] = g1[o]; bbv[oi] = b1[o]; eev[oi] = be1[o]; sbv[oi] = sb[o];
    }
    #pragma unroll
    for (int j = 0; j < 8; ++j) {
        int s = s0 + sg * 8 + j;
        uint64_t pz = 0, ps = 0;
        #pragma unroll
        for (int oi = 0; oi < 4; ++oi) {
            float v = gg[oi] * (acc[oi][j] + bbv[oi]) + eev[oi];
            v = fmaxf(v, 0.f);
            pz |= (uint64_t)f2bf(v) << (16 * oi);
            ps |= (uint64_t)f2bf(scv[oi][j] + sbv[oi]) << (16 * oi);
        }
        *(uint64_t*)&z1[((size_t)b * 1026 + 1 + s) * 128 + o0] = pz;
        *(uint64_t*)&sc[((size_t)b * SGR + s) * 128 + o0] = ps;
    }
}

// MFMA conv body, 256 threads (4 waves: wr=o-half, wc=s-half, 4 of x 4 sf frags)
// MODE 0: relu(bn) -> padded buf; MODE 1: + sc shortcut; MODE 2: + residual, mean->gout
template <int MODE>
static __device__ __forceinline__ void conv_body(int cblk,
        const ushort_t* __restrict__ zin, const ushort_t* __restrict__ wb,
        const float* __restrict__ bias, const float* __restrict__ gam,
        const float* __restrict__ bet, const ushort_t* __restrict__ res,
        void* __restrict__ outp, ushort_t* __restrict__ zl) {
    int t = threadIdx.x;
    int b = cblk >> 3, s0 = (cblk & 7) << 7;
    const ushort_t* zg = zin + ((size_t)b * 1026 + s0) * 128;
    for (int idx = t; idx < 130 * 16; idx += 256) {
        int r = idx >> 4, c = idx & 15;
        *(short8v*)&zl[r * 128 + c * 8] = *(const short8v*)&zg[(size_t)r * 128 + ((c ^ (r & 7)) * 8)];
    }
    __syncthreads();
    int w = t >> 6, lane = t & 63;
    int wr = w >> 1, wc = w & 1;
    int l15 = lane & 15, lk = lane >> 4;
    f32x4 acc[4][4] = {};
    #pragma unroll
    for (int k = 0; k < 3; ++k) {
        const ushort_t* wk = wb + k * 16384;
        #pragma unroll
        for (int cc = 0; cc < 4; ++cc) {
            short8v a[4], bf[4];
            #pragma unroll
            for (int of = 0; of < 4; ++of)
                a[of] = *(const short8v*)&wk[(size_t)(wr * 64 + of * 16 + l15) * 128 + cc * 32 + lk * 8];
            #pragma unroll
            for (int sf = 0; sf < 4; ++sf) {
                int r = wc * 64 + sf * 16 + l15 + k;
                int chunk = (cc * 4 + lk) ^ (r & 7);
                bf[sf] = *(const short8v*)&zl[r * 128 + chunk * 8];
            }
            #pragma unroll
            for (int of = 0; of < 4; ++of)
                #pragma unroll
                for (int sf = 0; sf < 4; ++sf)
                    acc[of][sf] = __builtin_amdgcn_mfma_f32_16x16x32_bf16(a[of], bf[sf], acc[of][sf], 0, 0, 0);
        }
    }
    float psum[4][4];
    if (MODE == 2)
        #pragma unroll
        for (int of = 0; of < 4; ++of)
            #pragma unroll
            for (int r = 0; r < 4; ++r) psum[of][r] = 0.f;
    #pragma unroll
    for (int of = 0; of < 4; ++of) {
        int o_ = wr * 64 + of * 16 + lk * 4;
        float g4[4], b4[4], e4[4];
        *(float4*)g4 = *(const float4*)&gam[o_];
        *(float4*)b4 = *(const float4*)&bias[o_];
        *(float4*)e4 = *(const float4*)&bet[o_];
        #pragma unroll
        for (int sf = 0; sf < 4; ++sf) {
            int s_ = s0 + wc * 64 + sf * 16 + l15;
            float v[4];
            #pragma unroll
            for (int r = 0; r < 4; ++r) v[r] = g4[r] * (acc[of][sf][r] + b4[r]) + e4[r];
            if (MODE == 1) {
                uint2 rv = *(const uint2*)&res[((size_t)b * SGR + s_) * 128 + o_];
                v[0] += bflo(rv.x); v[1] += bfhi(rv.x);
                v[2] += bflo(rv.y); v[3] += bfhi(rv.y);
            }
            if (MODE == 2) {
                uint2 rv = *(const uint2*)&res[((size_t)b * 1026 + 1 + s_) * 128 + o_];
                v[0] += bflo(rv.x); v[1] += bfhi(rv.x);
                v[2] += bflo(rv.y); v[3] += bfhi(rv.y);
            }
            #pragma unroll
            for (int r = 0; r < 4; ++r) v[r] = fmaxf(v[r], 0.f);
            if (MODE <= 1) {
                uint64_t p = (uint64_t)f2bf(v[0]) | ((uint64_t)f2bf(v[1]) << 16) |
                             ((uint64_t)f2bf(v[2]) << 32) | ((uint64_t)f2bf(v[3]) << 48);
                *(uint64_t*)&((ushort_t*)outp)[((size_t)b * 1026 + 1 + s_) * 128 + o_] = p;
            } else {
                #pragma unroll
                for (int r = 0; r < 4; ++r) psum[of][r] += v[r];
            }
        }
    }
    if (MODE == 2) {
        float* gout = (float*)outp;
        #pragma unroll
        for (int of = 0; of < 4; ++of) {
            #pragma unroll
            for (int r = 0; r < 4; ++r) {
                float t2 = psum[of][r];
                t2 += __shfl_xor(t2, 1);
                t2 += __shfl_xor(t2, 2);
                t2 += __shfl_xor(t2, 4);
                t2 += __shfl_xor(t2, 8);
                if (l15 == 0)
                    atomicAdd(&gout[b * 128 + wr * 64 + of * 16 + lk * 4 + r], t2 * (1.0f / 1024.0f));
            }
        }
    }
}

// ---------------- merged launches ----------------

// L2: binA (256 blocks) + convA (1024 blocks)
__global__ __launch_bounds__(256) void k2_binA_convA(
        const int* __restrict__ row, const int* __restrict__ col,
        int* __restrict__ bucketFill, unsigned* __restrict__ region,
        const float* __restrict__ x, const float* __restrict__ wT1,
        const float* __restrict__ b1, const float* __restrict__ g1,
        const float* __restrict__ be1, const float* __restrict__ sw,
        const float* __restrict__ sb, ushort_t* __restrict__ zA,
        ushort_t* __restrict__ scb) {
    if (blockIdx.x < 256)
        binA_body(blockIdx.x, row, col, bucketFill, region);
    else
        convA_body(blockIdx.x - 256, x, wT1, b1, g1, be1, sw, sb, zA, scb);
}

// L3: binB (256) + convB = conv_mfma<1> (512)
__global__ __launch_bounds__(256) void k3_binB_convB(
        const unsigned* __restrict__ region, const int* __restrict__ bucketFill,
        unsigned* __restrict__ slots4, int* __restrict__ cnts, float* __restrict__ dinv,
        const ushort_t* __restrict__ zA, const ushort_t* __restrict__ wbB,
        const float* __restrict__ b2, const float* __restrict__ g2,
        const float* __restrict__ be2, const ushort_t* __restrict__ scb,
        ushort_t* __restrict__ f1) {
    __shared__ ushort_t zl[130 * 128];
    if (blockIdx.x < 256)
        binB_body(blockIdx.x, region, bucketFill, slots4, cnts, dinv);
    else
        conv_body<1>(blockIdx.x - 256, zA, wbB, b2, g2, be2, scb, f1, zl);
}

// L4: aggx (16384) + convC = conv_mfma<0> (512)
__global__ __launch_bounds__(256) void k4_aggx_convC(
        const float* __restrict__ x, const int* __restrict__ cnts,
        const float* __restrict__ dinv, unsigned* __restrict__ slots4,
        const float* __restrict__ W1, const float* __restrict__ b1g,
        ushort_t* __restrict__ h1out,
        const ushort_t* __restrict__ f1, const ushort_t* __restrict__ wbC,
        const float* __restrict__ b3, const float* __restrict__ g3,
        const float* __restrict__ be3, ushort_t* __restrict__ zA) {
    __shared__ ushort_t zl[130 * 128];
    if (blockIdx.x < 16384)
        aggx_body(blockIdx.x, x, cnts, dinv, slots4, W1, b1g, h1out);
    else
        conv_body<0>(blockIdx.x - 16384, f1, wbC, b3, g3, be3, nullptr, zA, zl);
}

// L6: gemm_relu (512) + convD = conv_mfma<2> (512)
__global__ __launch_bounds__(256) void k6_gemm_convD(
        const ushort_t* __restrict__ Y, const ushort_t* __restrict__ w2T,
        const float* __restrict__ gb2, float* __restrict__ hout,
        const ushort_t* __restrict__ zA, const ushort_t* __restrict__ wbD,
        const float* __restrict__ b4, const float* __restrict__ g4,
        const float* __restrict__ be4, const ushort_t* __restrict__ f1,
        float* __restrict__ gout) {
    __shared__ ushort_t zl[130 * 128];
    if (blockIdx.x < 512)
        gemm_body(blockIdx.x, Y, w2T, gb2, hout);
    else
        conv_body<2>(blockIdx.x - 512, zA, wbD, b4, g4, be4, f1, gout, zl);
}

// ---------------- launch ----------------

extern "C" void kernel_launch(void* const* d_in, const int* in_sizes, int n_in,
                              void* d_out, int out_size, void* d_ws, size_t ws_size,
                              hipStream_t stream) {
    const float* x    = (const float*)d_in[0];
    const int*   ei   = (const int*)d_in[1];
    const float* gW1  = (const float*)d_in[3];
    const float* gb1  = (const float*)d_in[4];
    const float* gW2  = (const float*)d_in[5];
    const float* gb2  = (const float*)d_in[6];
    const float* r1w1 = (const float*)d_in[7];
    const float* r1b1 = (const float*)d_in[8];
    const float* r1g1 = (const float*)d_in[9];
    const float* r1be1= (const float*)d_in[10];
    const float* r1w2 = (const float*)d_in[11];
    const float* r1b2 = (const float*)d_in[12];
    const float* r1g2 = (const float*)d_in[13];
    const float* r1be2= (const float*)d_in[14];
    const float* r1sw = (const float*)d_in[15];
    const float* r1sb = (const float*)d_in[16];
    const float* r2w1 = (const float*)d_in[17];
    const float* r2b1 = (const float*)d_in[18];
    const float* r2g1 = (const float*)d_in[19];
    const float* r2be1= (const float*)d_in[20];
    const float* r2w2 = (const float*)d_in[21];
    const float* r2b2 = (const float*)d_in[22];
    const float* r2g2 = (const float*)d_in[23];
    const float* r2be2= (const float*)d_in[24];

    float* hout = (float*)d_out;
    float* gout = (float*)d_out + (size_t)NN * HH;

    // workspace (~85 MB). Lifetime-checked aliases:
    //  region (L2w,L3r) lives inside bufT (L5w,L6r); h1 (L4w,L5r) aliases scb (L2w,L3r).
    ushort_t* bufT = (ushort_t*)d_ws;                 // NN*128 bf16: Y (agg2 out)
    ushort_t* zA   = bufT + (size_t)NN * 128;         // 64*1026*128 padded (z1, then z2)
    ushort_t* f1   = zA + (size_t)64 * 1026 * 128;    // 64*1026*128 padded
    ushort_t* scb  = f1 + (size_t)64 * 1026 * 128;    // 64*1024*128 (sc, then h1)
    unsigned* slots4 = (unsigned*)(scb + (size_t)64 * 1024 * 128);  // NN*64 uints
    ushort_t* wbB  = (ushort_t*)(slots4 + (size_t)NN * SSTRIDE);    // 3*128*128
    ushort_t* wbC  = wbB + 49152;
    ushort_t* wbD  = wbC + 49152;
    ushort_t* w2T  = wbD + 49152;                     // 128*128
    float* wT1     = (float*)(w2T + 16384);           // 4*3*128 fp32
    float* dinv    = wT1 + 1536;                      // NN
    int* cnts      = (int*)(dinv + NN);               // NN
    int* bucketFill= cnts + NN;                       // 256
    unsigned* region = (unsigned*)bufT;               // 256*BCAP, aliased in bufT

    const int* row = ei;
    const int* col = ei + NE;
    ushort_t* h1buf = scb;

    // L1: prep
    prep_k<<<743, 256, 0, stream>>>(r1w1, r1w2, r2w1, r2w2, gW2,
                                    wT1, wbB, wbC, wbD, w2T, zA, f1, gout, bucketFill);
    // L2: binA + convA
    k2_binA_convA<<<256 + BGR * 16, 256, 0, stream>>>(
        row, col, bucketFill, region,
        x, wT1, r1b1, r1g1, r1be1, r1sw, r1sb, zA, scb);
    // L3: binB + convB
    k3_binB_convB<<<256 + BGR * 8, 256, 0, stream>>>(
        region, bucketFill, slots4, cnts, dinv,
        zA, wbB, r1b2, r1g2, r1be2, scb, f1);
    // L4: aggx + convC
    k4_aggx_convC<<<NN / 4 + BGR * 8, 256, 0, stream>>>(
        x, cnts, dinv, slots4, gW1, gb1, h1buf,
        f1, wbC, r2b1, r2g1, r2be1, zA);
    // L5: agg2 (solo, full occupancy)
    agg2y_k<<<NN / 16, 256, 0, stream>>>(h1buf, cnts, slots4, bufT);
    // L6: gemm (bias+relu, fp32 out) + convD
    k6_gemm_convD<<<512 + BGR * 8, 256, 0, stream>>>(
        bufT, w2T, gb2, hout,
        zA, wbD, r2b2, r2g2, r2be2, f1, gout);
}